// Round 1
// baseline (3469.947 us; speedup 1.0000x reference)
//
#include <hip/hip_runtime.h>
#include <cstdint>
#include <cstddef>

// ---------------- workspace layout (floats) ----------------
// e1      [4,16,256,256] 4194304
// e2      [4,32,128,128] 2097152
// e3a     [4,64,64,64]   1048576
// e3b     [4,64,64,64]   1048576
// big16   s1 [4,16,256,256] then d2raw [4,16,256,256]  4194304
// big8    s2 [4,32,128,128] then d3 [4,32,128,128]     2097152
// b4      s3 [4,64,64,64] then bn-out                  1048576
// v       [4,64,4096] 1048576
// q       [4,8,4096]  131072
// k       [4,8,4096]  131072
// pool    [4,64,8,8]  16384
// sf1     [4,64] 256
// sf2     [4,64] 256
// rowstat 16384
// d2lf    [4,16,256,256] 4194304
// preout  [4,3,256,256]  786432
static const size_t OFF_E1    = 0;
static const size_t OFF_E2    = 4194304;
static const size_t OFF_E3A   = 6291456;
static const size_t OFF_E3B   = 7340032;
static const size_t OFF_BIG16 = 8388608;
static const size_t OFF_BIG8  = 12582912;
static const size_t OFF_B4    = 14680064;
static const size_t OFF_V     = 15728640;
static const size_t OFF_Q     = 16777216;
static const size_t OFF_K     = 16908288;
static const size_t OFF_POOL  = 17039360;
static const size_t OFF_SF1   = 17055744;
static const size_t OFF_SF2   = 17056000;
static const size_t OFF_ROW   = 17056256;
static const size_t OFF_D2LF  = 17072640;
static const size_t OFF_PRE   = 21266944;
// total = 22053376 floats = 88.2 MB

// ---------------- conv 3x3 stride1 pad1, optional 2-input concat ----------------
// in2 may be spatially-broadcast (style_feat): value in2[b*C2+c] at every pixel
__global__ __launch_bounds__(256) void k_conv3x3(
    const float* __restrict__ in1, int C1,
    const float* __restrict__ in2, int C2, int bcast2,
    const float* __restrict__ w, const float* __restrict__ bias,
    float* __restrict__ out, int B, int H, int W, int Cout, int relu)
{
  long idx = (long)blockIdx.x * 256 + threadIdx.x;
  long total = (long)B * Cout * H * W;
  if (idx >= total) return;
  int ow = (int)(idx % W); long t = idx / W;
  int oh = (int)(t % H); t /= H;
  int co = (int)(t % Cout); int b = (int)(t / Cout);
  int Cin = C1 + C2;
  float acc = bias[co];
  const float* wco = w + (long)co * Cin * 9;
  for (int ci = 0; ci < Cin; ++ci) {
    const float* wp = wco + ci * 9;
    bool is2 = ci >= C1;
    float bval = 0.f;
    const float* src = nullptr;
    if (is2 && bcast2) {
      bval = in2[b * C2 + (ci - C1)];
    } else {
      src = is2 ? (in2 + ((long)(b * C2 + ci - C1)) * H * W)
                : (in1 + ((long)(b * C1 + ci)) * H * W);
    }
#pragma unroll
    for (int ky = 0; ky < 3; ++ky) {
      int ih = oh + ky - 1;
      if ((unsigned)ih >= (unsigned)H) continue;
#pragma unroll
      for (int kx = 0; kx < 3; ++kx) {
        int iw = ow + kx - 1;
        if ((unsigned)iw >= (unsigned)W) continue;
        float xv = (is2 && bcast2) ? bval : src[ih * W + iw];
        acc += wp[ky * 3 + kx] * xv;
      }
    }
  }
  if (relu) acc = fmaxf(acc, 0.f);
  out[idx] = acc;
}

// ---------------- conv 4x4 stride2 pad1 + relu ----------------
__global__ __launch_bounds__(256) void k_conv4x4s2(
    const float* __restrict__ in, const float* __restrict__ w,
    const float* __restrict__ bias, float* __restrict__ out,
    int B, int Cin, int Hin, int Win, int Cout)
{
  int Ho = Hin >> 1, Wo = Win >> 1;
  long idx = (long)blockIdx.x * 256 + threadIdx.x;
  long total = (long)B * Cout * Ho * Wo;
  if (idx >= total) return;
  int ow = (int)(idx % Wo); long t = idx / Wo;
  int oh = (int)(t % Ho); t /= Ho;
  int co = (int)(t % Cout); int b = (int)(t / Cout);
  float acc = bias[co];
  const float* wco = w + (long)co * Cin * 16;
  for (int ci = 0; ci < Cin; ++ci) {
    const float* src = in + ((long)(b * Cin + ci)) * Hin * Win;
    const float* wp = wco + ci * 16;
#pragma unroll
    for (int ky = 0; ky < 4; ++ky) {
      int ih = oh * 2 - 1 + ky;
      if ((unsigned)ih >= (unsigned)Hin) continue;
#pragma unroll
      for (int kx = 0; kx < 4; ++kx) {
        int iw = ow * 2 - 1 + kx;
        if ((unsigned)iw >= (unsigned)Win) continue;
        acc += wp[ky * 4 + kx] * src[ih * Win + iw];
      }
    }
  }
  out[idx] = fmaxf(acc, 0.f);
}

// ---------------- convT 4x4 stride2 pad1 + relu (2-input concat) ----------------
// weight layout [Cin, Cout, 4, 4] (PyTorch ConvTranspose2d)
__global__ __launch_bounds__(256) void k_convt4x4(
    const float* __restrict__ in1, int C1,
    const float* __restrict__ in2, int C2,
    const float* __restrict__ w, const float* __restrict__ bias,
    float* __restrict__ out, int B, int Hin, int Win, int Cout)
{
  int Ho = Hin * 2, Wo = Win * 2;
  long idx = (long)blockIdx.x * 256 + threadIdx.x;
  long total = (long)B * Cout * Ho * Wo;
  if (idx >= total) return;
  int ow = (int)(idx % Wo); long t = idx / Wo;
  int oh = (int)(t % Ho); t /= Ho;
  int co = (int)(t % Cout); int b = (int)(t / Cout);
  int Cin = C1 + C2;
  int ky0 = (oh + 1) & 1, kx0 = (ow + 1) & 1;
  int ih0 = (oh + 1 - ky0) >> 1;
  int iw0 = (ow + 1 - kx0) >> 1;
  float acc = bias[co];
  for (int ci = 0; ci < Cin; ++ci) {
    const float* src = (ci < C1) ? (in1 + ((long)(b * C1 + ci)) * Hin * Win)
                                 : (in2 + ((long)(b * C2 + ci - C1)) * Hin * Win);
    const float* wp = w + ((long)ci * Cout + co) * 16;
#pragma unroll
    for (int kk = 0; kk < 2; ++kk) {
      int ky = ky0 + 2 * kk; int ih = ih0 - kk;
      if ((unsigned)ih >= (unsigned)Hin) continue;
#pragma unroll
      for (int jj = 0; jj < 2; ++jj) {
        int kx = kx0 + 2 * jj; int iw = iw0 - jj;
        if ((unsigned)iw >= (unsigned)Win) continue;
        acc += wp[ky * 4 + kx] * src[ih * Win + iw];
      }
    }
  }
  out[idx] = fmaxf(acc, 0.f);
}

// ---------------- conv1x1 (no relu) ----------------
__global__ __launch_bounds__(256) void k_conv1x1(
    const float* __restrict__ in, const float* __restrict__ w,
    const float* __restrict__ bias, float* __restrict__ out,
    int B, int Cin, int Cout, int N)
{
  long idx = (long)blockIdx.x * 256 + threadIdx.x;
  long total = (long)B * Cout * N;
  if (idx >= total) return;
  int n = (int)(idx % N); long t = idx / N;
  int co = (int)(t % Cout); int b = (int)(t / Cout);
  float acc = bias[co];
  const float* wp = w + (long)co * Cin;
  const float* src = in + ((long)b * Cin) * N + n;
  for (int ci = 0; ci < Cin; ++ci) acc += wp[ci] * src[(long)ci * N];
  out[idx] = acc;
}

// ---------------- adaptive avg pool to 8x8 ----------------
__global__ __launch_bounds__(256) void k_pool8(
    const float* __restrict__ in, float* __restrict__ out, int B, int C, int H, int W)
{
  int idx = blockIdx.x * 256 + threadIdx.x;
  int total = B * C * 64;
  if (idx >= total) return;
  int ow = idx & 7, oh = (idx >> 3) & 7;
  int c = (idx >> 6) % C, b = idx / (64 * C);
  int bh = H / 8, bw = W / 8;
  const float* src = in + ((long)(b * C + c)) * H * W;
  float s = 0.f;
  for (int y = 0; y < bh; ++y)
    for (int x = 0; x < bw; ++x)
      s += src[(oh * bh + y) * W + ow * bw + x];
  out[idx] = s / (float)(bh * bw);
}

// ---------------- fc + relu (wave per output) ----------------
__global__ __launch_bounds__(256) void k_fc_relu(
    const float* __restrict__ in, const float* __restrict__ w,
    const float* __restrict__ bias, float* __restrict__ out, int B, int K, int O)
{
  int gi = blockIdx.x * 4 + (threadIdx.x >> 6);
  int lane = threadIdx.x & 63;
  if (gi >= B * O) return;
  int b = gi / O, o = gi % O;
  const float* x = in + (long)b * K;
  const float* wp = w + (long)o * K;
  float s = 0.f;
  for (int i = lane; i < K; i += 64) s += x[i] * wp[i];
#pragma unroll
  for (int d = 1; d < 64; d <<= 1) s += __shfl_xor(s, d);
  if (lane == 0) out[gi] = fmaxf(s + bias[o], 0.f);
}

// ---------------- e3 = e3b*0.99 + e3a*0.01 (into a) ----------------
__global__ __launch_bounds__(256) void k_mix(
    float* __restrict__ a, const float* __restrict__ bfilt, long n)
{
  long idx = (long)blockIdx.x * 256 + threadIdx.x;
  if (idx >= n) return;
  a[idx] = bfilt[idx] * 0.99f + a[idx] * 0.01f;
}

// ---------------- line filter: per-row std -> sigmoid mask ----------------
__global__ __launch_bounds__(256) void k_lf_rowstat(
    const float* __restrict__ x, float* __restrict__ mask_raw, int rows, int W)
{
  int row = blockIdx.x * 4 + (threadIdx.x >> 6);
  int lane = threadIdx.x & 63;
  if (row >= rows) return;
  const float* p = x + (long)row * W;
  float s = 0.f;
  for (int i = lane; i < W; i += 64) s += p[i];
#pragma unroll
  for (int d = 1; d < 64; d <<= 1) s += __shfl_xor(s, d);
  float mean = s / (float)W;
  float v = 0.f;
  for (int i = lane; i < W; i += 64) { float t = p[i] - mean; v += t * t; }
#pragma unroll
  for (int d = 1; d < 64; d <<= 1) v += __shfl_xor(v, d);
  float stdv = sqrtf(v / (float)(W - 1));
  float mask = 1.f / (1.f + __expf(-(0.05f - stdv) * 10.f));
  if (lane == 0) mask_raw[row] = mask;
}

// ---------------- line filter apply (+optional tanh) ----------------
__global__ __launch_bounds__(256) void k_lf_apply(
    const float* __restrict__ x, const float* __restrict__ mask_raw,
    float* __restrict__ out, int BC, int H, int W, float strength, int do_tanh)
{
  long idx = (long)blockIdx.x * 256 + threadIdx.x;
  long total = (long)BC * H * W;
  if (idx >= total) return;
  int wcol = (int)(idx % W);
  int h = (int)((idx / W) % H);
  int bc = (int)(idx / ((long)W * H));
  const float* px = x + (long)bc * H * W;
  const float* pm = mask_raw + (long)bc * H;
  float vs = 0.f, mb = 0.f;
#pragma unroll
  for (int d = -2; d <= 2; ++d) {
    int hh = h + d; hh = hh < 0 ? 0 : (hh >= H ? H - 1 : hh);
    vs += px[hh * W + wcol];
    mb += pm[hh];
  }
  vs *= 0.2f; mb *= 0.2f;
  float m = mb * strength;
  float o = x[idx] * (1.f - m) + vs * m;
  if (do_tanh) o = tanhf(o);
  out[idx] = o;
}

// ---------------- fused self-attention (flash-style, 4 query rows / block) ----
#define ATT_TN 4
__global__ __launch_bounds__(256) void k_attn(
    const float* __restrict__ qb, const float* __restrict__ kb,
    const float* __restrict__ vb, const float* __restrict__ xb,
    const float* __restrict__ gamma_p, float* __restrict__ outb, int N)
{
  __shared__ float e[ATT_TN][4096];
  __shared__ float wred[ATT_TN][4];
  __shared__ float rowm[ATT_TN];
  __shared__ float rows_[ATT_TN];
  __shared__ float pvred[4][64][ATT_TN];

  int tid = threadIdx.x;
  int lane = tid & 63, wid = tid >> 6;
  int nb = N / ATT_TN;
  int b = blockIdx.x / nb;
  int n0 = (blockIdx.x % nb) * ATT_TN;

  float qr[ATT_TN][8];
#pragma unroll
  for (int r = 0; r < ATT_TN; ++r)
#pragma unroll
    for (int c = 0; c < 8; ++c)
      qr[r][c] = qb[((long)b * 8 + c) * N + n0 + r];

  float lmax[ATT_TN];
#pragma unroll
  for (int r = 0; r < ATT_TN; ++r) lmax[r] = -1e30f;
  for (int j = 0; j < 16; ++j) {
    int m = j * 256 + tid;
    float kv[8];
#pragma unroll
    for (int c = 0; c < 8; ++c) kv[c] = kb[((long)b * 8 + c) * N + m];
#pragma unroll
    for (int r = 0; r < ATT_TN; ++r) {
      float s = 0.f;
#pragma unroll
      for (int c = 0; c < 8; ++c) s += qr[r][c] * kv[c];
      e[r][m] = s;
      lmax[r] = fmaxf(lmax[r], s);
    }
  }
#pragma unroll
  for (int r = 0; r < ATT_TN; ++r)
#pragma unroll
    for (int d = 1; d < 64; d <<= 1) lmax[r] = fmaxf(lmax[r], __shfl_xor(lmax[r], d));
  if (lane == 0)
    for (int r = 0; r < ATT_TN; ++r) wred[r][wid] = lmax[r];
  __syncthreads();
  if (tid < ATT_TN) {
    float m = wred[tid][0];
    for (int w2 = 1; w2 < 4; ++w2) m = fmaxf(m, wred[tid][w2]);
    rowm[tid] = m;
  }
  __syncthreads();
  float rm[ATT_TN];
#pragma unroll
  for (int r = 0; r < ATT_TN; ++r) rm[r] = rowm[r];

  float lsum[ATT_TN] = {0.f, 0.f, 0.f, 0.f};
  for (int j = 0; j < 16; ++j) {
    int m = j * 256 + tid;
#pragma unroll
    for (int r = 0; r < ATT_TN; ++r) {
      float p = __expf(e[r][m] - rm[r]);
      e[r][m] = p;
      lsum[r] += p;
    }
  }
#pragma unroll
  for (int r = 0; r < ATT_TN; ++r)
#pragma unroll
    for (int d = 1; d < 64; d <<= 1) lsum[r] += __shfl_xor(lsum[r], d);
  if (lane == 0)
    for (int r = 0; r < ATT_TN; ++r) wred[r][wid] = lsum[r];
  __syncthreads();
  if (tid < ATT_TN) {
    rows_[tid] = wred[tid][0] + wred[tid][1] + wred[tid][2] + wred[tid][3];
  }
  __syncthreads();

  // PV: thread (qq, c) covers m in [qq*1024, qq*1024+1024)
  int c = tid & 63, qq = tid >> 6;
  float acc[ATT_TN] = {0.f, 0.f, 0.f, 0.f};
  const float* vrow = vb + ((long)b * 64 + c) * N + qq * (N / 4);
  for (int mm = 0; mm < N / 4; ++mm) {
    float vv = vrow[mm];
    int m = qq * (N / 4) + mm;
#pragma unroll
    for (int r = 0; r < ATT_TN; ++r) acc[r] += e[r][m] * vv;
  }
#pragma unroll
  for (int r = 0; r < ATT_TN; ++r) pvred[qq][c][r] = acc[r];
  __syncthreads();
  if (tid < 64) {
    float g = gamma_p[0];
#pragma unroll
    for (int r = 0; r < ATT_TN; ++r) {
      float s = pvred[0][tid][r] + pvred[1][tid][r] + pvred[2][tid][r] + pvred[3][tid][r];
      long o = ((long)b * 64 + tid) * N + n0 + r;
      outb[o] = g * (s / rows_[r]) + xb[o];
    }
  }
}

// ---------------- launch ----------------
static inline unsigned gdiv(long total) { return (unsigned)((total + 255) / 256); }

extern "C" void kernel_launch(void* const* d_in, const int* in_sizes, int n_in,
                              void* d_out, int out_size, void* d_ws, size_t ws_size,
                              hipStream_t stream)
{
  (void)in_sizes; (void)n_in; (void)out_size; (void)ws_size;
  const float* sketch   = (const float*)d_in[0];
  const float* depth    = (const float*)d_in[1];
  const float* style    = (const float*)d_in[2];
  const float* enc1_w   = (const float*)d_in[3];
  const float* enc1_b   = (const float*)d_in[4];
  const float* enc2_w   = (const float*)d_in[5];
  const float* enc2_b   = (const float*)d_in[6];
  const float* enc3_w   = (const float*)d_in[7];
  const float* enc3_b   = (const float*)d_in[8];
  const float* se1_w    = (const float*)d_in[9];
  const float* se1_b    = (const float*)d_in[10];
  const float* se2_w    = (const float*)d_in[11];
  const float* se2_b    = (const float*)d_in[12];
  const float* se3_w    = (const float*)d_in[13];
  const float* se3_b    = (const float*)d_in[14];
  const float* sp1_w    = (const float*)d_in[15];
  const float* sp1_b    = (const float*)d_in[16];
  const float* sp2_w    = (const float*)d_in[17];
  const float* sp2_b    = (const float*)d_in[18];
  const float* sm_w     = (const float*)d_in[19];
  const float* sm_b     = (const float*)d_in[20];
  const float* attn_q_w = (const float*)d_in[21];
  const float* attn_q_b = (const float*)d_in[22];
  const float* attn_k_w = (const float*)d_in[23];
  const float* attn_k_b = (const float*)d_in[24];
  const float* attn_v_w = (const float*)d_in[25];
  const float* attn_v_b = (const float*)d_in[26];
  const float* attn_g   = (const float*)d_in[27];
  const float* bn_w     = (const float*)d_in[28];
  const float* bn_b     = (const float*)d_in[29];
  const float* dec3_w   = (const float*)d_in[30];
  const float* dec3_b   = (const float*)d_in[31];
  const float* dec2_w   = (const float*)d_in[32];
  const float* dec2_b   = (const float*)d_in[33];
  const float* dec1_w   = (const float*)d_in[34];
  const float* dec1_b   = (const float*)d_in[35];
  float* out = (float*)d_out;

  float* ws    = (float*)d_ws;
  float* e1    = ws + OFF_E1;
  float* e2    = ws + OFF_E2;
  float* e3a   = ws + OFF_E3A;
  float* e3b   = ws + OFF_E3B;
  float* big16 = ws + OFF_BIG16;
  float* big8  = ws + OFF_BIG8;
  float* b4    = ws + OFF_B4;
  float* vbuf  = ws + OFF_V;
  float* qbuf  = ws + OFF_Q;
  float* kbuf  = ws + OFF_K;
  float* pool  = ws + OFF_POOL;
  float* sf1   = ws + OFF_SF1;
  float* sf2   = ws + OFF_SF2;
  float* rowst = ws + OFF_ROW;
  float* d2lf  = ws + OFF_D2LF;
  float* pre   = ws + OFF_PRE;

  const int B = 4;

  // ---- encoder ----
  k_conv3x3<<<gdiv((long)B*16*256*256), 256, 0, stream>>>(
      sketch, 1, depth, 1, 0, enc1_w, enc1_b, e1, B, 256, 256, 16, 1);
  k_conv4x4s2<<<gdiv((long)B*32*128*128), 256, 0, stream>>>(
      e1, enc2_w, enc2_b, e2, B, 16, 256, 256, 32);
  k_conv4x4s2<<<gdiv((long)B*64*64*64), 256, 0, stream>>>(
      e2, enc3_w, enc3_b, e3a, B, 32, 128, 128, 64);
  // line_filter(e3, 0.8): e3a -> e3b
  k_lf_rowstat<<<(B*64*64 + 3)/4, 256, 0, stream>>>(e3a, rowst, B*64*64, 64);
  k_lf_apply<<<gdiv((long)B*64*64*64), 256, 0, stream>>>(
      e3a, rowst, e3b, B*64, 64, 64, 0.8f, 0);

  // ---- style branch ----
  k_conv3x3<<<gdiv((long)B*16*256*256), 256, 0, stream>>>(
      style, 3, nullptr, 0, 0, se1_w, se1_b, big16, B, 256, 256, 16, 1);
  k_conv4x4s2<<<gdiv((long)B*32*128*128), 256, 0, stream>>>(
      big16, se2_w, se2_b, big8, B, 16, 256, 256, 32);
  k_conv4x4s2<<<gdiv((long)B*64*64*64), 256, 0, stream>>>(
      big8, se3_w, se3_b, b4, B, 32, 128, 128, 64);
  k_pool8<<<gdiv(B*64*64), 256, 0, stream>>>(b4, pool, B, 64, 64, 64);
  k_fc_relu<<<(B*64 + 3)/4, 256, 0, stream>>>(pool, sp1_w, sp1_b, sf1, B, 4096, 64);
  k_fc_relu<<<(B*64 + 3)/4, 256, 0, stream>>>(sf1, sp2_w, sp2_b, sf2, B, 64, 64);

  // ---- style merge: conv3x3(concat(e3b, broadcast sf2)) -> e3a ; mix ----
  k_conv3x3<<<gdiv((long)B*64*64*64), 256, 0, stream>>>(
      e3b, 64, sf2, 64, 1, sm_w, sm_b, e3a, B, 64, 64, 64, 1);
  k_mix<<<gdiv((long)B*64*64*64), 256, 0, stream>>>(e3a, e3b, (long)B*64*64*64);

  // ---- self-attention on e3a -> e3b ----
  k_conv1x1<<<gdiv((long)B*8*4096), 256, 0, stream>>>(e3a, attn_q_w, attn_q_b, qbuf, B, 64, 8, 4096);
  k_conv1x1<<<gdiv((long)B*8*4096), 256, 0, stream>>>(e3a, attn_k_w, attn_k_b, kbuf, B, 64, 8, 4096);
  k_conv1x1<<<gdiv((long)B*64*4096), 256, 0, stream>>>(e3a, attn_v_w, attn_v_b, vbuf, B, 64, 64, 4096);
  k_attn<<<B * (4096 / ATT_TN), 256, 0, stream>>>(qbuf, kbuf, vbuf, e3a, attn_g, e3b, 4096);

  // ---- bottleneck + decoder ----
  k_conv3x3<<<gdiv((long)B*64*64*64), 256, 0, stream>>>(
      e3b, 64, nullptr, 0, 0, bn_w, bn_b, b4, B, 64, 64, 64, 1);
  k_convt4x4<<<gdiv((long)B*32*128*128), 256, 0, stream>>>(
      b4, 64, e3b, 64, dec3_w, dec3_b, big8, B, 64, 64, 32);
  k_convt4x4<<<gdiv((long)B*16*256*256), 256, 0, stream>>>(
      big8, 32, e2, 32, dec2_w, dec2_b, big16, B, 128, 128, 16);
  // line_filter(d2, 0.8): big16 -> d2lf
  k_lf_rowstat<<<(B*16*256 + 3)/4, 256, 0, stream>>>(big16, rowst, B*16*256, 256);
  k_lf_apply<<<gdiv((long)B*16*256*256), 256, 0, stream>>>(
      big16, rowst, d2lf, B*16, 256, 256, 0.8f, 0);
  // dec1: conv3x3(concat(d2lf, e1)) -> pre (no relu)
  k_conv3x3<<<gdiv((long)B*3*256*256), 256, 0, stream>>>(
      d2lf, 16, e1, 16, 0, dec1_w, dec1_b, pre, B, 256, 256, 3, 0);
  // final: tanh(line_filter(pre, 0.9)) -> out
  k_lf_rowstat<<<(B*3*256 + 3)/4, 256, 0, stream>>>(pre, rowst, B*3*256, 256);
  k_lf_apply<<<gdiv((long)B*3*256*256), 256, 0, stream>>>(
      pre, rowst, out, B*3, 256, 256, 0.9f, 1);
}